// Round 7
// baseline (166.467 us; speedup 1.0000x reference)
//
#include <hip/hip_runtime.h>
#include <hip/hip_bf16.h>

// Problem: x(4,256,64,64), offset(4,18,64,64), mask(4,9,64,64),
// weight(256,256,3,3) -> out(4,256,64,64). stride=1, pad=1, K=3.
// R7: sample kernel split by kk (grid 512 -> 4608) for 9x memory-latency
// concurrency (R6: sample was latency-bound at 14% occupancy, 53 us).
// GEMM stays LDS-free (R6 win): fragment-ready A'/B' blocked layouts,
// direct global->VGPR dwordx4 fragment loads, 3-buffer register pipeline.
//   A'[mb 0..127][kc 0..287][row 0..127] of 16B chunks (8 bf16)
//   B'[ob 0..3]  [kc 0..287][row 0..63]  of 16B chunks
#define BN 4
#define CN 256
#define HN 64
#define WN 64
#define ON 256
#define KKN 9
#define HWN 4096
#define KDIM 2304   // 9*256
#define MN 16384    // B*H*W
#define KC 288      // KDIM/8 chunks

using frag_ab = __attribute__((ext_vector_type(8))) short;  // 8 bf16
using frag_cd = __attribute__((ext_vector_type(4))) float;  // 4 fp32

static __device__ inline short f2bf(float f) {
    union { float f; unsigned u; } v; v.f = f;
    unsigned r = v.u + 0x7fffu + ((v.u >> 16) & 1u);
    return (short)(r >> 16);
}
static __device__ inline float bf2f(short s) {
    union { unsigned u; float f; } v; v.u = ((unsigned)(unsigned short)s) << 16;
    return v.f;
}

// ---------- kernel 1: prep = transpose x -> BHWC bf16 | repack weight ------
__global__ __launch_bounds__(256) void prep_kernel(const float* __restrict__ x,
                                                   const float* __restrict__ wsrc,
                                                   short* __restrict__ xb16,
                                                   short* __restrict__ wtb) {
    int bidx = blockIdx.x;
    int tid  = threadIdx.x;
    if (bidx < 1024) {
        __shared__ float tile[64][65];
        int b   = bidx >> 8;
        int rem = bidx & 255;
        int c0  = (rem >> 6) * 64;
        int p0  = (rem & 63) * 64;
        int tp = tid & 63, tc = tid >> 6;
        for (int i = 0; i < 16; ++i) {
            int c = tc + i * 4;
            tile[c][tp] = x[(b * CN + c0 + c) * HWN + p0 + tp];
        }
        __syncthreads();
        int tcc = tid & 63, tpp = tid >> 6;
        for (int i = 0; i < 16; ++i) {
            int p = tpp + i * 4;
            xb16[(b * HWN + p0 + p) * CN + c0 + tcc] = f2bf(tile[tcc][p]);
        }
    } else {
        int chunk = (bidx - 1024) * 256 + tid;   // < 4*288*64 = 73728
        int ob  = chunk / (KC * 64);
        int rem = chunk - ob * (KC * 64);
        int kc  = rem >> 6;
        int row = rem & 63;
        int o   = ob * 64 + row;
        int kk  = kc >> 5;
        int oct = kc & 31;
        frag_ab v;
        #pragma unroll
        for (int e = 0; e < 8; ++e)
            v[e] = f2bf(wsrc[(o * CN + oct * 8 + e) * 9 + kk]);
        *(frag_ab*)&wtb[(size_t)chunk * 8] = v;
    }
}

// ---------- kernel 2: sample -> A'[mb][kc][row] bf16 chunks ----------
// grid 4608: bid = kk*512 + og*128 + mb. thread: row = t&127 (m = mb*128+row),
// sub = t>>7 -> 4 octs starting at og*8+sub*4. One kk per block.
__global__ __launch_bounds__(256) void sample_kernel(const short* __restrict__ xb16,
                                                     const float* __restrict__ offs,
                                                     const float* __restrict__ maskp,
                                                     short* __restrict__ A) {
    int bidx = blockIdx.x;
    int kk   = bidx >> 9;
    int og   = (bidx >> 7) & 3;
    int mb   = bidx & 127;
    int t    = threadIdx.x;
    int row  = t & 127;
    int sub  = t >> 7;
    int m = mb * 128 + row;
    int b = m >> 12;
    int h = (m >> 6) & 63;
    int w = m & 63;
    int oct0 = og * 8 + sub * 4;

    int ki = kk / 3, kj = kk - ki * 3;
    int obase = ((b * 18 + kk * 2) * 64 + h) * 64 + w;
    float dy = offs[obase];
    float dx = offs[obase + HWN];
    float mv = maskp[((b * 9 + kk) * 64 + h) * 64 + w];
    float py = (float)(h - 1 + ki) + dy;
    float px = (float)(w - 1 + kj) + dx;
    float y0f = floorf(py), x0f = floorf(px);
    float wy = py - y0f, wx = px - x0f;
    int y0 = (int)y0f, x0 = (int)x0f;
    const short* rp[4];
    float cw[4];
    #pragma unroll
    for (int cy = 0; cy < 2; ++cy)
        #pragma unroll
        for (int cx = 0; cx < 2; ++cx) {
            int yy = y0 + cy, xx = x0 + cx;
            bool valid = (yy >= 0 && yy < HN && xx >= 0 && xx < WN);
            int yc = min(max(yy, 0), HN - 1);
            int xc = min(max(xx, 0), WN - 1);
            rp[cy * 2 + cx] = xb16 + (size_t)(((b * HN + yc) * WN + xc)) * CN;
            float wgt = (cy ? wy : 1.f - wy) * (cx ? wx : 1.f - wx) * mv;
            cw[cy * 2 + cx] = valid ? wgt : 0.f;
        }
    #pragma unroll
    for (int oc = 0; oc < 4; ++oc) {
        int oct = oct0 + oc;
        frag_ab v0 = *(const frag_ab*)(rp[0] + oct * 8);
        frag_ab v1 = *(const frag_ab*)(rp[1] + oct * 8);
        frag_ab v2 = *(const frag_ab*)(rp[2] + oct * 8);
        frag_ab v3 = *(const frag_ab*)(rp[3] + oct * 8);
        frag_ab res;
        #pragma unroll
        for (int e = 0; e < 8; e += 2) {
            float a0 = cw[0] * bf2f(v0[e]) + cw[1] * bf2f(v1[e])
                     + cw[2] * bf2f(v2[e]) + cw[3] * bf2f(v3[e]);
            float a1 = cw[0] * bf2f(v0[e + 1]) + cw[1] * bf2f(v1[e + 1])
                     + cw[2] * bf2f(v2[e + 1]) + cw[3] * bf2f(v3[e + 1]);
            __hip_bfloat162 p2 = __float22bfloat162_rn(make_float2(a0, a1));
            res[e]     = *(short*)&p2.x;
            res[e + 1] = *(short*)&p2.y;
        }
        int kc = kk * 32 + oct;
        *(frag_ab*)&A[(((size_t)mb * KC + kc) * 128 + row) * 8] = res;
    }
}

// ---------- kernel 3: LDS-free GEMM. MT=128, NT=64, grid 512 ----------
// K-step ks (=32 k): af(i) at A' chunk (ks*4+q)*128 + wv*32+i*16+r;
// bf(j) at B' chunk (ks*4+q)*64 + j*16+r. 72 steps, 3-buffer rotation.
#define MT 128
#define NT 64

__global__ __launch_bounds__(256, 2) void gemm_kernel(const short* __restrict__ A,
                                                      const short* __restrict__ wtb,
                                                      float* __restrict__ out) {
    __shared__ float outb[MT][65];   // epilogue transpose only
    int tid  = threadIdx.x;
    int bid  = blockIdx.x;
    int mblk = bid & 127;            // A-tile sharers land on one XCD
    int oblk = bid >> 7;
    int m0 = mblk * MT, o0 = oblk * NT;
    int wv = tid >> 6, lane = tid & 63;
    int q = lane >> 4, r = lane & 15;

    frag_cd acc[2][4];
    #pragma unroll
    for (int i = 0; i < 2; ++i)
        #pragma unroll
        for (int j = 0; j < 4; ++j)
            acc[i][j] = (frag_cd){0.f, 0.f, 0.f, 0.f};

    // lane-fixed bases (short units). ks strides: A 4096, B 2048. i/j: 128.
    const short* ap = A   + ((size_t)mblk * KC + q) * 1024 + (wv * 32 + r) * 8;
    const short* bp = wtb + ((size_t)oblk * KC + q) * 512 + r * 8;

    frag_ab af0[2], af1[2], af2[2], bf0[4], bf1[4], bf2[4];

#define LOADK(AF, BF, ks)                                                  \
    {                                                                      \
        const short* a_ = ap + (size_t)(ks) * 4096;                        \
        AF[0] = *(const frag_ab*)(a_);                                     \
        AF[1] = *(const frag_ab*)(a_ + 128);                               \
        const short* b_ = bp + (size_t)(ks) * 2048;                        \
        BF[0] = *(const frag_ab*)(b_);                                     \
        BF[1] = *(const frag_ab*)(b_ + 128);                               \
        BF[2] = *(const frag_ab*)(b_ + 256);                               \
        BF[3] = *(const frag_ab*)(b_ + 384);                               \
    }

#define MFMAK(AF, BF)                                                      \
    {                                                                      \
        _Pragma("unroll")                                                  \
        for (int i = 0; i < 2; ++i) {                                      \
            _Pragma("unroll")                                              \
            for (int j = 0; j < 4; ++j)                                    \
                acc[i][j] = __builtin_amdgcn_mfma_f32_16x16x32_bf16(       \
                    AF[i], BF[j], acc[i][j], 0, 0, 0);                     \
        }                                                                  \
    }

    LOADK(af0, bf0, 0)
    LOADK(af1, bf1, 1)
    for (int kt = 0; kt < 23; ++kt) {
        int ks = kt * 3;
        LOADK(af2, bf2, ks + 2)
        MFMAK(af0, bf0)
        LOADK(af0, bf0, ks + 3)
        MFMAK(af1, bf1)
        LOADK(af1, bf1, ks + 4)
        MFMAK(af2, bf2)
    }
    // peel ks = 69,70,71 (69,70 already loaded; load 71)
    LOADK(af2, bf2, 71)
    MFMAK(af0, bf0)
    MFMAK(af1, bf1)
    MFMAK(af2, bf2)

    // ---- epilogue: C-frag (row = q*4+reg, col = r) -> LDS -> BOHW ----
    #pragma unroll
    for (int i = 0; i < 2; ++i)
        #pragma unroll
        for (int j = 0; j < 4; ++j) {
            int ml = wv * 32 + i * 16 + q * 4;
            int ol = j * 16 + r;
            outb[ml + 0][ol] = acc[i][j][0];
            outb[ml + 1][ol] = acc[i][j][1];
            outb[ml + 2][ol] = acc[i][j][2];
            outb[ml + 3][ol] = acc[i][j][3];
        }
    __syncthreads();
    int b = m0 >> 12, h0 = (m0 >> 6) & 63;
    int w = tid & 63, sub = tid >> 6;
    #pragma unroll
    for (int oo = 0; oo < 16; ++oo) {
        int ol = oo * 4 + sub;
        #pragma unroll
        for (int hh = 0; hh < 2; ++hh) {
            out[(((size_t)b * ON + o0 + ol) * HN + h0 + hh) * WN + w] =
                outb[hh * 64 + w][ol];
        }
    }
}

extern "C" void kernel_launch(void* const* d_in, const int* in_sizes, int n_in,
                              void* d_out, int out_size, void* d_ws, size_t ws_size,
                              hipStream_t stream) {
    const float* x      = (const float*)d_in[0];
    const float* offset = (const float*)d_in[1];
    const float* mask   = (const float*)d_in[2];
    const float* weight = (const float*)d_in[3];
    float* out = (float*)d_out;

    // ws: xb16 bf16 8 MiB | wtb bf16 1.125 MiB | A' bf16 72 MiB
    short* xb16 = (short*)d_ws;
    short* wtb  = (short*)((char*)d_ws + 8388608);
    short* A    = (short*)((char*)d_ws + 8388608 + 1179648);

    hipLaunchKernelGGL(prep_kernel,   dim3(1312), dim3(256), 0, stream,
                       x, weight, xb16, wtb);
    hipLaunchKernelGGL(sample_kernel, dim3(4608), dim3(256), 0, stream,
                       xb16, offset, mask, A);
    hipLaunchKernelGGL(gemm_kernel,   dim3(512),  dim3(256), 0, stream,
                       A, wtb, out);
}